// Round 2
// baseline (499.446 us; speedup 1.0000x reference)
//
#include <hip/hip_runtime.h>

constexpr int B = 8, N = 512, E = 65536;
constexpr int D_IN = 128, D_H = 64, R_IN = 32, R_OUT = 32;
constexpr int NT = B * N;
constexpr size_t NN = (size_t)B * N * N;   // 2,097,152

// ---------------------------------------------------------------------------
// psi_1 pre-projection: xr[n][j] = b1[j] + sum_k x[n][k]*Wr[k][j]
//                       xn[n][j] =         sum_k x[n][k]*Wn[k][j]
// (project BEFORE scatter: halves atomic channel count 128 -> 64)
// ---------------------------------------------------------------------------
__global__ void psi1_project(const float* __restrict__ x,
                             const float* __restrict__ Wr,
                             const float* __restrict__ Wn,
                             const float* __restrict__ b,
                             float* __restrict__ xr,
                             float* __restrict__ xn) {
  __shared__ float xs[D_IN];
  const int n = blockIdx.x;
  const int j = threadIdx.x;                      // 64 threads = 1 wave
  for (int c = j; c < D_IN; c += 64) xs[c] = x[(size_t)n * D_IN + c];
  __syncthreads();
  float ar = b[j], an = 0.f;
#pragma unroll 4
  for (int k = 0; k < D_IN; ++k) {
    const float xv = xs[k];
    ar += xv * Wr[k * D_H + j];
    an += xv * Wn[k * D_H + j];
  }
  xr[(size_t)n * D_H + j] = ar;
  xn[(size_t)n * D_H + j] = an;
}

// agg[dst][c] += xn[src][c] * ea[e], 64 channels, float4 per thread
__global__ void scatter64(const float* __restrict__ xn,
                          const int* __restrict__ src,
                          const int* __restrict__ dst,
                          const float* __restrict__ ea,
                          float* __restrict__ agg) {
  const int tid = blockIdx.x * blockDim.x + threadIdx.x;
  const int e = tid >> 4;
  if (e >= E) return;
  const int c4 = (tid & 15) * 4;
  const float w = ea[e];
  const float4 v = *(const float4*)(xn + (size_t)src[e] * D_H + c4);
  float* a = agg + (size_t)dst[e] * D_H + c4;
  atomicAdd(a + 0, v.x * w);
  atomicAdd(a + 1, v.y * w);
  atomicAdd(a + 2, v.z * w);
  atomicAdd(a + 3, v.w * w);
}

// agg[dst][c] += r[src][c] * ea[e], 32 channels
__global__ void scatter32(const float* __restrict__ rn,
                          const int* __restrict__ src,
                          const int* __restrict__ dst,
                          const float* __restrict__ ea,
                          float* __restrict__ agg) {
  const int tid = blockIdx.x * blockDim.x + threadIdx.x;
  const int e = tid >> 3;
  if (e >= E) return;
  const int c4 = (tid & 7) * 4;
  const float w = ea[e];
  const float4 v = *(const float4*)(rn + (size_t)src[e] * R_IN + c4);
  float* a = agg + (size_t)dst[e] * R_IN + c4;
  atomicAdd(a + 0, v.x * w);
  atomicAdd(a + 1, v.y * w);
  atomicAdd(a + 2, v.z * w);
  atomicAdd(a + 3, v.w * w);
}

// ---------------------------------------------------------------------------
// S_hat0[b,s,t] = dot(relu(xr_s+ag_s)[b,s,:], relu(xr_t+ag_t)[b,t,:])  (K=64)
// relu fused into the LDS load; h never materialized.
// 32x32 output tile per 256-thread block; rows padded to 65 for bank spread.
// ---------------------------------------------------------------------------
__global__ void gemm_score64(const float* __restrict__ xr_s, const float* __restrict__ ag_s,
                             const float* __restrict__ xr_t, const float* __restrict__ ag_t,
                             float* __restrict__ C) {
  __shared__ float As[32][65];
  __shared__ float Bs[32][65];
  const int b = blockIdx.z;
  const int s0 = blockIdx.y * 32, t0 = blockIdx.x * 32;
  const int tid = threadIdx.x;  // 256
  for (int i = tid; i < 512; i += 256) {
    const int r = i >> 4, c4 = (i & 15) * 4;
    {
      const size_t idx = ((size_t)(b * N + s0 + r)) * D_H + c4;
      const float4 a1 = *(const float4*)(xr_s + idx);
      const float4 a2 = *(const float4*)(ag_s + idx);
      As[r][c4 + 0] = fmaxf(a1.x + a2.x, 0.f);
      As[r][c4 + 1] = fmaxf(a1.y + a2.y, 0.f);
      As[r][c4 + 2] = fmaxf(a1.z + a2.z, 0.f);
      As[r][c4 + 3] = fmaxf(a1.w + a2.w, 0.f);
    }
    {
      const size_t idx = ((size_t)(b * N + t0 + r)) * D_H + c4;
      const float4 b1v = *(const float4*)(xr_t + idx);
      const float4 b2v = *(const float4*)(ag_t + idx);
      Bs[r][c4 + 0] = fmaxf(b1v.x + b2v.x, 0.f);
      Bs[r][c4 + 1] = fmaxf(b1v.y + b2v.y, 0.f);
      Bs[r][c4 + 2] = fmaxf(b1v.z + b2v.z, 0.f);
      Bs[r][c4 + 3] = fmaxf(b1v.w + b2v.w, 0.f);
    }
  }
  __syncthreads();
  const int ls = tid >> 3;            // 0..31 (s within tile)
  const int lt0 = (tid & 7) * 4;      // t base: 4 consecutive outputs
  float acc0 = 0, acc1 = 0, acc2 = 0, acc3 = 0;
#pragma unroll 8
  for (int k = 0; k < 64; ++k) {
    const float a = As[ls][k];
    acc0 += a * Bs[lt0 + 0][k];
    acc1 += a * Bs[lt0 + 1][k];
    acc2 += a * Bs[lt0 + 2][k];
    acc3 += a * Bs[lt0 + 3][k];
  }
  float4* out = (float4*)(C + ((size_t)b * N + s0 + ls) * N + t0 + lt0);
  *out = make_float4(acc0, acc1, acc2, acc3);
}

// ---------------------------------------------------------------------------
// row softmax over 512 cols, one block (256 thr = 4 waves) per row
// ---------------------------------------------------------------------------
__global__ void softmax512(const float* __restrict__ X, float* __restrict__ Y) {
  __shared__ float red[8];
  const int row = blockIdx.x;
  const float* xr = X + (size_t)row * N;
  float* yr = Y + (size_t)row * N;
  const int t = threadIdx.x;
  const float2 v = *(const float2*)(xr + t * 2);
  float m = fmaxf(v.x, v.y);
#pragma unroll
  for (int o = 32; o; o >>= 1) m = fmaxf(m, __shfl_down(m, o));
  if ((t & 63) == 0) red[t >> 6] = m;
  __syncthreads();
  const float M = fmaxf(fmaxf(red[0], red[1]), fmaxf(red[2], red[3]));
  const float e0 = __expf(v.x - M), e1 = __expf(v.y - M);
  float s = e0 + e1;
#pragma unroll
  for (int o = 32; o; o >>= 1) s += __shfl_down(s, o);
  if ((t & 63) == 0) red[4 + (t >> 6)] = s;
  __syncthreads();
  const float inv = 1.0f / (red[4] + red[5] + red[6] + red[7]);
  *(float2*)(yr + t * 2) = make_float2(e0 * inv, e1 * inv);
}

// ---------------------------------------------------------------------------
// r_t[b,t,r] = sum_s S[b,s,t] * r_s[b,s,r]
// ---------------------------------------------------------------------------
__global__ void rt_kernel(const float* __restrict__ S, const float* __restrict__ rs,
                          float* __restrict__ rt) {
  __shared__ float Ss[32][33];
  __shared__ float Rs[32][32];
  const int b = blockIdx.y;
  const int t0 = blockIdx.x * 32;
  const float* Sb = S + (size_t)b * N * N;
  const float* rb = rs + (size_t)b * N * R_IN;
  const int tid = threadIdx.x;   // 256
  const int lt = tid >> 3;       // 0..31
  const int r0 = (tid & 7) * 4;  // 4 r per thread
  float a0 = 0, a1 = 0, a2 = 0, a3 = 0;
  for (int s0 = 0; s0 < N; s0 += 32) {
    for (int i = tid; i < 1024; i += 256) {
      const int ss = i >> 5, cc = i & 31;
      Ss[ss][cc] = Sb[(size_t)(s0 + ss) * N + t0 + cc];
      Rs[ss][cc] = rb[(size_t)(s0 + ss) * R_IN + cc];
    }
    __syncthreads();
#pragma unroll 8
    for (int ss = 0; ss < 32; ++ss) {
      const float sv = Ss[ss][lt];
      a0 += sv * Rs[ss][r0 + 0];
      a1 += sv * Rs[ss][r0 + 1];
      a2 += sv * Rs[ss][r0 + 2];
      a3 += sv * Rs[ss][r0 + 3];
    }
    __syncthreads();
  }
  float4* out = (float4*)(rt + ((size_t)b * N + t0 + lt) * R_IN + r0);
  *out = make_float4(a0, a1, a2, a3);
}

// ---------------------------------------------------------------------------
// psi_2 dense + Wm1 projection fused:
//   o = relu(r@W2r + agg@W2n + b2);  P = o@Wm1 (+ bm1 if addBm1)
// ---------------------------------------------------------------------------
__global__ void psi2_dense(const float* __restrict__ r, const float* __restrict__ agg,
                           const float* __restrict__ W2r, const float* __restrict__ W2n,
                           const float* __restrict__ b2,
                           const float* __restrict__ Wm1, const float* __restrict__ bm1,
                           int addBm1, float* __restrict__ P) {
  __shared__ float os[8][33];
  const int g = threadIdx.x >> 5;
  const int j = threadIdx.x & 31;
  const int n = blockIdx.x * 8 + g;
  const float* rrow = r + (size_t)n * R_IN;
  const float* arow = agg + (size_t)n * R_IN;
  float acc = b2[j];
#pragma unroll 8
  for (int k = 0; k < 32; ++k)
    acc += rrow[k] * W2r[k * 32 + j] + arow[k] * W2n[k * 32 + j];
  os[g][j] = fmaxf(acc, 0.f);
  __syncthreads();
  float p = addBm1 ? bm1[j] : 0.f;
#pragma unroll 8
  for (int k = 0; k < 32; ++k) p += os[g][k] * Wm1[k * 32 + j];
  P[(size_t)n * 32 + j] = p;
}

// ---------------------------------------------------------------------------
// S_hat[b,s,t] += relu(P_s[b,s,:] - P_t[b,t,:]) . Wm2 + bm2
// ---------------------------------------------------------------------------
__global__ void consensus_update(const float* __restrict__ Ps, const float* __restrict__ Pt,
                                 const float* __restrict__ Wm2, const float* __restrict__ bm2,
                                 float* __restrict__ Sh) {
  __shared__ float PsS[32][33], PtS[32][33];
  __shared__ float w2[32];
  const int b = blockIdx.z, s0 = blockIdx.y * 32, t0 = blockIdx.x * 32;
  const int tid = threadIdx.x;  // 256
  for (int i = tid; i < 1024; i += 256) {
    const int rr = i >> 5, cc = i & 31;
    PsS[rr][cc] = Ps[((size_t)b * N + s0 + rr) * 32 + cc];
    PtS[rr][cc] = Pt[((size_t)b * N + t0 + rr) * 32 + cc];
  }
  if (tid < 32) w2[tid] = Wm2[tid];
  __syncthreads();
  const float bb = bm2[0];
  const int ls = tid >> 3;         // 0..31
  const int lt0 = (tid & 7) * 4;   // 4 consecutive t
  float a0 = bb, a1 = bb, a2 = bb, a3 = bb;
#pragma unroll 8
  for (int k = 0; k < 32; ++k) {
    const float ps = PsS[ls][k];
    const float w = w2[k];
    a0 += fmaxf(ps - PtS[lt0 + 0][k], 0.f) * w;
    a1 += fmaxf(ps - PtS[lt0 + 1][k], 0.f) * w;
    a2 += fmaxf(ps - PtS[lt0 + 2][k], 0.f) * w;
    a3 += fmaxf(ps - PtS[lt0 + 3][k], 0.f) * w;
  }
  float4* p = (float4*)(Sh + ((size_t)b * N + s0 + ls) * N + t0 + lt0);
  float4 o = *p;
  o.x += a0; o.y += a1; o.z += a2; o.w += a3;
  *p = o;
}

// ---------------------------------------------------------------------------
extern "C" void kernel_launch(void* const* d_in, const int* in_sizes, int n_in,
                              void* d_out, int out_size, void* d_ws, size_t ws_size,
                              hipStream_t stream) {
  const float* x_s  = (const float*)d_in[0];
  const int*   ei_s = (const int*)d_in[1];
  const float* ea_s = (const float*)d_in[2];
  const float* x_t  = (const float*)d_in[4];
  const int*   ei_t = (const int*)d_in[5];
  const float* ea_t = (const float*)d_in[6];
  const float* r_all = (const float*)d_in[8];
  const float* W1r = (const float*)d_in[9];
  const float* W1n = (const float*)d_in[10];
  const float* b1  = (const float*)d_in[11];
  const float* W2r = (const float*)d_in[12];
  const float* W2n = (const float*)d_in[13];
  const float* b2  = (const float*)d_in[14];
  const float* Wm1 = (const float*)d_in[15];
  const float* bm1 = (const float*)d_in[16];
  const float* Wm2 = (const float*)d_in[17];
  const float* bm2 = (const float*)d_in[18];

  const int* src_s = ei_s;
  const int* dst_s = ei_s + E;
  const int* src_t = ei_t;
  const int* dst_t = ei_t + E;

  float* ws = (float*)d_ws;
  float* xr_s = ws; ws += (size_t)NT * D_H;
  float* xn_s = ws; ws += (size_t)NT * D_H;
  float* xr_t = ws; ws += (size_t)NT * D_H;
  float* xn_t = ws; ws += (size_t)NT * D_H;
  float* ag_s = ws; ws += (size_t)NT * D_H;
  float* ag_t = ws; ws += (size_t)NT * D_H;
  float* Shat = ws; ws += NN;
  float* Sbuf = ws; ws += NN;
  float* rt_b = ws; ws += (size_t)NT * R_IN;
  float* ag2s = ws; ws += (size_t)NT * R_IN;
  float* ag2t = ws; ws += (size_t)NT * R_IN;
  float* Psb  = ws; ws += (size_t)NT * R_OUT;
  float* Ptb  = ws; ws += (size_t)NT * R_OUT;

  float* S0_out = (float*)d_out;
  float* SL_out = S0_out + NN;

  hipMemsetAsync(ag_s, 0, (size_t)NT * D_H * sizeof(float), stream);
  hipMemsetAsync(ag_t, 0, (size_t)NT * D_H * sizeof(float), stream);

  psi1_project<<<NT, 64, 0, stream>>>(x_s, W1r, W1n, b1, xr_s, xn_s);
  psi1_project<<<NT, 64, 0, stream>>>(x_t, W1r, W1n, b1, xr_t, xn_t);
  scatter64<<<E * 16 / 256, 256, 0, stream>>>(xn_s, src_s, dst_s, ea_s, ag_s);
  scatter64<<<E * 16 / 256, 256, 0, stream>>>(xn_t, src_t, dst_t, ea_t, ag_t);
  gemm_score64<<<dim3(16, 16, B), 256, 0, stream>>>(xr_s, ag_s, xr_t, ag_t, Shat);

  for (int step = 0; step < 2; ++step) {
    float* S = (step == 0) ? S0_out : Sbuf;          // step-0 softmax IS S_0
    softmax512<<<B * N, 256, 0, stream>>>(Shat, S);
    const float* rs = r_all + (size_t)step * NT * R_IN;
    rt_kernel<<<dim3(16, B), 256, 0, stream>>>(S, rs, rt_b);
    hipMemsetAsync(ag2s, 0, (size_t)NT * R_IN * sizeof(float), stream);
    hipMemsetAsync(ag2t, 0, (size_t)NT * R_IN * sizeof(float), stream);
    scatter32<<<E * 8 / 256, 256, 0, stream>>>(rs, src_s, dst_s, ea_s, ag2s);
    scatter32<<<E * 8 / 256, 256, 0, stream>>>(rt_b, src_t, dst_t, ea_t, ag2t);
    psi2_dense<<<NT / 8, 256, 0, stream>>>(rs, ag2s, W2r, W2n, b2, Wm1, bm1, 1, Psb);
    psi2_dense<<<NT / 8, 256, 0, stream>>>(rt_b, ag2t, W2r, W2n, b2, Wm1, bm1, 0, Ptb);
    consensus_update<<<dim3(16, 16, B), 256, 0, stream>>>(Psb, Ptb, Wm2, bm2, Shat);
  }
  softmax512<<<B * N, 256, 0, stream>>>(Shat, SL_out);
}

// Round 3
// 345.267 us; speedup vs baseline: 1.4466x; 1.4466x over previous
//
#include <hip/hip_runtime.h>

constexpr int B = 8, N = 512, E = 65536;
constexpr int D_IN = 128, D_H = 64, R_IN = 32, R_OUT = 32;
constexpr int NT = B * N;
constexpr size_t NN = (size_t)B * N * N;   // 2,097,152

// ---------------------------------------------------------------------------
// psi_1 pre-projection: xr[n][j] = b1[j] + sum_k x[n][k]*Wr[k][j]
//                       xn[n][j] =         sum_k x[n][k]*Wn[k][j]
// (project BEFORE aggregation: 64 channels instead of 128)
// ---------------------------------------------------------------------------
__global__ void psi1_project(const float* __restrict__ x,
                             const float* __restrict__ Wr,
                             const float* __restrict__ Wn,
                             const float* __restrict__ b,
                             float* __restrict__ xr,
                             float* __restrict__ xn) {
  __shared__ float xs[D_IN];
  const int n = blockIdx.x;
  const int j = threadIdx.x;                      // 64 threads = 1 wave
  for (int c = j; c < D_IN; c += 64) xs[c] = x[(size_t)n * D_IN + c];
  __syncthreads();
  float ar = b[j], an = 0.f;
#pragma unroll 4
  for (int k = 0; k < D_IN; ++k) {
    const float xv = xs[k];
    ar += xv * Wr[k * D_H + j];
    an += xv * Wn[k * D_H + j];
  }
  xr[(size_t)n * D_H + j] = ar;
  xn[(size_t)n * D_H + j] = an;
}

// ---------------------------------------------------------------------------
// CSR-by-dst build (per call, deterministic enough: slot order varies only
// within a bucket -> fp sum order, same as reference's segment_sum tolerance).
// Replaces 4.2M float write-through atomics with 2x65K int atomics.
// ---------------------------------------------------------------------------
__global__ void degree_k(const int* __restrict__ dst, int* __restrict__ deg) {
  const int e = blockIdx.x * 256 + threadIdx.x;
  if (e < E) atomicAdd(&deg[dst[e]], 1);
}

// exclusive prefix over NT=4096 degrees; writes rowptr[0..NT] and cursor copy
__global__ void scan_nodes(const int* __restrict__ deg, int* __restrict__ rowptr,
                           int* __restrict__ cursor) {
  __shared__ int ps[256];
  const int t = threadIdx.x;            // 256 threads, 16 nodes each
  const int base = t * 16;
  int loc[16];
  int s = 0;
#pragma unroll
  for (int i = 0; i < 16; ++i) { loc[i] = s; s += deg[base + i]; }
  ps[t] = s;
  __syncthreads();
  for (int off = 1; off < 256; off <<= 1) {   // Hillis-Steele inclusive
    const int add = (t >= off) ? ps[t - off] : 0;
    __syncthreads();
    ps[t] += add;
    __syncthreads();
  }
  const int excl = ps[t] - s;
#pragma unroll
  for (int i = 0; i < 16; ++i) {
    const int v = excl + loc[i];
    rowptr[base + i] = v;
    cursor[base + i] = v;
  }
  if (t == 255) rowptr[NT] = ps[255];
}

// pack (src, edge_weight) per slot so the gather does one 8B broadcast load
__global__ void fill_csr(const int* __restrict__ src, const int* __restrict__ dst,
                         const float* __restrict__ ea, int* __restrict__ cursor,
                         int2* __restrict__ pack) {
  const int e = blockIdx.x * 256 + threadIdx.x;
  if (e >= E) return;
  const int slot = atomicAdd(&cursor[dst[e]], 1);
  pack[slot] = make_int2(src[e], __float_as_int(ea[e]));
}

// agg[n][:] = sum_{edges e: dst=n} xn[src_e][:] * w_e   (64 ch, 16 thr/node)
__global__ void gather64(const float* __restrict__ xn, const int* __restrict__ rowptr,
                         const int2* __restrict__ pack, float* __restrict__ agg) {
  const int tid = blockIdx.x * 256 + threadIdx.x;
  const int n = tid >> 4;
  const int c4 = (tid & 15) * 4;
  const int beg = rowptr[n], end = rowptr[n + 1];
  float4 acc = make_float4(0.f, 0.f, 0.f, 0.f);
  for (int k = beg; k < end; ++k) {
    const int2 p = pack[k];
    const float w = __int_as_float(p.y);
    const float4 v = *(const float4*)(xn + (size_t)p.x * D_H + c4);
    acc.x += v.x * w; acc.y += v.y * w; acc.z += v.z * w; acc.w += v.w * w;
  }
  *(float4*)(agg + (size_t)n * D_H + c4) = acc;
}

// same, 32 channels, 8 thr/node
__global__ void gather32(const float* __restrict__ rn, const int* __restrict__ rowptr,
                         const int2* __restrict__ pack, float* __restrict__ agg) {
  const int tid = blockIdx.x * 256 + threadIdx.x;
  const int n = tid >> 3;
  const int c4 = (tid & 7) * 4;
  const int beg = rowptr[n], end = rowptr[n + 1];
  float4 acc = make_float4(0.f, 0.f, 0.f, 0.f);
  for (int k = beg; k < end; ++k) {
    const int2 p = pack[k];
    const float w = __int_as_float(p.y);
    const float4 v = *(const float4*)(rn + (size_t)p.x * R_IN + c4);
    acc.x += v.x * w; acc.y += v.y * w; acc.z += v.z * w; acc.w += v.w * w;
  }
  *(float4*)(agg + (size_t)n * R_IN + c4) = acc;
}

// ---------------------------------------------------------------------------
// S_hat0[b,s,t] = dot(relu(xr_s+ag_s)[b,s,:], relu(xr_t+ag_t)[b,t,:])  (K=64)
// relu fused into the LDS load; h never materialized.
// ---------------------------------------------------------------------------
__global__ void gemm_score64(const float* __restrict__ xr_s, const float* __restrict__ ag_s,
                             const float* __restrict__ xr_t, const float* __restrict__ ag_t,
                             float* __restrict__ C) {
  __shared__ float As[32][65];
  __shared__ float Bs[32][65];
  const int b = blockIdx.z;
  const int s0 = blockIdx.y * 32, t0 = blockIdx.x * 32;
  const int tid = threadIdx.x;  // 256
  for (int i = tid; i < 512; i += 256) {
    const int r = i >> 4, c4 = (i & 15) * 4;
    {
      const size_t idx = ((size_t)(b * N + s0 + r)) * D_H + c4;
      const float4 a1 = *(const float4*)(xr_s + idx);
      const float4 a2 = *(const float4*)(ag_s + idx);
      As[r][c4 + 0] = fmaxf(a1.x + a2.x, 0.f);
      As[r][c4 + 1] = fmaxf(a1.y + a2.y, 0.f);
      As[r][c4 + 2] = fmaxf(a1.z + a2.z, 0.f);
      As[r][c4 + 3] = fmaxf(a1.w + a2.w, 0.f);
    }
    {
      const size_t idx = ((size_t)(b * N + t0 + r)) * D_H + c4;
      const float4 b1v = *(const float4*)(xr_t + idx);
      const float4 b2v = *(const float4*)(ag_t + idx);
      Bs[r][c4 + 0] = fmaxf(b1v.x + b2v.x, 0.f);
      Bs[r][c4 + 1] = fmaxf(b1v.y + b2v.y, 0.f);
      Bs[r][c4 + 2] = fmaxf(b1v.z + b2v.z, 0.f);
      Bs[r][c4 + 3] = fmaxf(b1v.w + b2v.w, 0.f);
    }
  }
  __syncthreads();
  const int ls = tid >> 3;            // 0..31 (s within tile)
  const int lt0 = (tid & 7) * 4;      // 4 consecutive t
  float acc0 = 0, acc1 = 0, acc2 = 0, acc3 = 0;
#pragma unroll 8
  for (int k = 0; k < 64; ++k) {
    const float a = As[ls][k];
    acc0 += a * Bs[lt0 + 0][k];
    acc1 += a * Bs[lt0 + 1][k];
    acc2 += a * Bs[lt0 + 2][k];
    acc3 += a * Bs[lt0 + 3][k];
  }
  float4* out = (float4*)(C + ((size_t)b * N + s0 + ls) * N + t0 + lt0);
  *out = make_float4(acc0, acc1, acc2, acc3);
}

// ---------------------------------------------------------------------------
// row softmax over 512 cols, one block (256 thr = 4 waves) per row
// ---------------------------------------------------------------------------
__global__ void softmax512(const float* __restrict__ X, float* __restrict__ Y) {
  __shared__ float red[8];
  const int row = blockIdx.x;
  const float* xr = X + (size_t)row * N;
  float* yr = Y + (size_t)row * N;
  const int t = threadIdx.x;
  const float2 v = *(const float2*)(xr + t * 2);
  float m = fmaxf(v.x, v.y);
#pragma unroll
  for (int o = 32; o; o >>= 1) m = fmaxf(m, __shfl_down(m, o));
  if ((t & 63) == 0) red[t >> 6] = m;
  __syncthreads();
  const float M = fmaxf(fmaxf(red[0], red[1]), fmaxf(red[2], red[3]));
  const float e0 = __expf(v.x - M), e1 = __expf(v.y - M);
  float s = e0 + e1;
#pragma unroll
  for (int o = 32; o; o >>= 1) s += __shfl_down(s, o);
  if ((t & 63) == 0) red[4 + (t >> 6)] = s;
  __syncthreads();
  const float inv = 1.0f / (red[4] + red[5] + red[6] + red[7]);
  *(float2*)(yr + t * 2) = make_float2(e0 * inv, e1 * inv);
}

// ---------------------------------------------------------------------------
// r_t[b,t,r] = sum_s S[b,s,t] * r_s[b,s,r]
// ---------------------------------------------------------------------------
__global__ void rt_kernel(const float* __restrict__ S, const float* __restrict__ rs,
                          float* __restrict__ rt) {
  __shared__ float Ss[32][33];
  __shared__ float Rs[32][32];
  const int b = blockIdx.y;
  const int t0 = blockIdx.x * 32;
  const float* Sb = S + (size_t)b * N * N;
  const float* rb = rs + (size_t)b * N * R_IN;
  const int tid = threadIdx.x;   // 256
  const int lt = tid >> 3;       // 0..31
  const int r0 = (tid & 7) * 4;  // 4 r per thread
  float a0 = 0, a1 = 0, a2 = 0, a3 = 0;
  for (int s0 = 0; s0 < N; s0 += 32) {
    for (int i = tid; i < 1024; i += 256) {
      const int ss = i >> 5, cc = i & 31;
      Ss[ss][cc] = Sb[(size_t)(s0 + ss) * N + t0 + cc];
      Rs[ss][cc] = rb[(size_t)(s0 + ss) * R_IN + cc];
    }
    __syncthreads();
#pragma unroll 8
    for (int ss = 0; ss < 32; ++ss) {
      const float sv = Ss[ss][lt];
      a0 += sv * Rs[ss][r0 + 0];
      a1 += sv * Rs[ss][r0 + 1];
      a2 += sv * Rs[ss][r0 + 2];
      a3 += sv * Rs[ss][r0 + 3];
    }
    __syncthreads();
  }
  float4* out = (float4*)(rt + ((size_t)b * N + t0 + lt) * R_IN + r0);
  *out = make_float4(a0, a1, a2, a3);
}

// ---------------------------------------------------------------------------
// psi_2 dense + Wm1 projection fused:
//   o = relu(r@W2r + agg@W2n + b2);  P = o@Wm1 (+ bm1 if addBm1)
// ---------------------------------------------------------------------------
__global__ void psi2_dense(const float* __restrict__ r, const float* __restrict__ agg,
                           const float* __restrict__ W2r, const float* __restrict__ W2n,
                           const float* __restrict__ b2,
                           const float* __restrict__ Wm1, const float* __restrict__ bm1,
                           int addBm1, float* __restrict__ P) {
  __shared__ float os[8][33];
  const int g = threadIdx.x >> 5;
  const int j = threadIdx.x & 31;
  const int n = blockIdx.x * 8 + g;
  const float* rrow = r + (size_t)n * R_IN;
  const float* arow = agg + (size_t)n * R_IN;
  float acc = b2[j];
#pragma unroll 8
  for (int k = 0; k < 32; ++k)
    acc += rrow[k] * W2r[k * 32 + j] + arow[k] * W2n[k * 32 + j];
  os[g][j] = fmaxf(acc, 0.f);
  __syncthreads();
  float p = addBm1 ? bm1[j] : 0.f;
#pragma unroll 8
  for (int k = 0; k < 32; ++k) p += os[g][k] * Wm1[k * 32 + j];
  P[(size_t)n * 32 + j] = p;
}

// ---------------------------------------------------------------------------
// S_hat[b,s,t] += relu(P_s[b,s,:] - P_t[b,t,:]) . Wm2 + bm2
// ---------------------------------------------------------------------------
__global__ void consensus_update(const float* __restrict__ Ps, const float* __restrict__ Pt,
                                 const float* __restrict__ Wm2, const float* __restrict__ bm2,
                                 float* __restrict__ Sh) {
  __shared__ float PsS[32][33], PtS[32][33];
  __shared__ float w2[32];
  const int b = blockIdx.z, s0 = blockIdx.y * 32, t0 = blockIdx.x * 32;
  const int tid = threadIdx.x;  // 256
  for (int i = tid; i < 1024; i += 256) {
    const int rr = i >> 5, cc = i & 31;
    PsS[rr][cc] = Ps[((size_t)b * N + s0 + rr) * 32 + cc];
    PtS[rr][cc] = Pt[((size_t)b * N + t0 + rr) * 32 + cc];
  }
  if (tid < 32) w2[tid] = Wm2[tid];
  __syncthreads();
  const float bb = bm2[0];
  const int ls = tid >> 3;         // 0..31
  const int lt0 = (tid & 7) * 4;   // 4 consecutive t
  float a0 = bb, a1 = bb, a2 = bb, a3 = bb;
#pragma unroll 8
  for (int k = 0; k < 32; ++k) {
    const float ps = PsS[ls][k];
    const float w = w2[k];
    a0 += fmaxf(ps - PtS[lt0 + 0][k], 0.f) * w;
    a1 += fmaxf(ps - PtS[lt0 + 1][k], 0.f) * w;
    a2 += fmaxf(ps - PtS[lt0 + 2][k], 0.f) * w;
    a3 += fmaxf(ps - PtS[lt0 + 3][k], 0.f) * w;
  }
  float4* p = (float4*)(Sh + ((size_t)b * N + s0 + ls) * N + t0 + lt0);
  float4 o = *p;
  o.x += a0; o.y += a1; o.z += a2; o.w += a3;
  *p = o;
}

// ---------------------------------------------------------------------------
extern "C" void kernel_launch(void* const* d_in, const int* in_sizes, int n_in,
                              void* d_out, int out_size, void* d_ws, size_t ws_size,
                              hipStream_t stream) {
  const float* x_s  = (const float*)d_in[0];
  const int*   ei_s = (const int*)d_in[1];
  const float* ea_s = (const float*)d_in[2];
  const float* x_t  = (const float*)d_in[4];
  const int*   ei_t = (const int*)d_in[5];
  const float* ea_t = (const float*)d_in[6];
  const float* r_all = (const float*)d_in[8];
  const float* W1r = (const float*)d_in[9];
  const float* W1n = (const float*)d_in[10];
  const float* b1  = (const float*)d_in[11];
  const float* W2r = (const float*)d_in[12];
  const float* W2n = (const float*)d_in[13];
  const float* b2  = (const float*)d_in[14];
  const float* Wm1 = (const float*)d_in[15];
  const float* bm1 = (const float*)d_in[16];
  const float* Wm2 = (const float*)d_in[17];
  const float* bm2 = (const float*)d_in[18];

  const int* src_s = ei_s;
  const int* dst_s = ei_s + E;
  const int* src_t = ei_t;
  const int* dst_t = ei_t + E;

  float* ws = (float*)d_ws;
  float* xr_s = ws; ws += (size_t)NT * D_H;
  float* xn_s = ws; ws += (size_t)NT * D_H;
  float* xr_t = ws; ws += (size_t)NT * D_H;
  float* xn_t = ws; ws += (size_t)NT * D_H;
  float* ag_s = ws; ws += (size_t)NT * D_H;
  float* ag_t = ws; ws += (size_t)NT * D_H;
  float* Shat = ws; ws += NN;
  float* Sbuf = ws; ws += NN;
  float* rt_b = ws; ws += (size_t)NT * R_IN;
  float* ag2s = ws; ws += (size_t)NT * R_IN;
  float* ag2t = ws; ws += (size_t)NT * R_IN;
  float* Psb  = ws; ws += (size_t)NT * R_OUT;
  float* Ptb  = ws; ws += (size_t)NT * R_OUT;
  // CSR scratch (all offsets stay 8B-aligned: every size is even)
  int* deg_s    = (int*)ws; ws += NT;
  int* rowptr_s = (int*)ws; ws += NT + 2;
  int* cursor_s = (int*)ws; ws += NT;
  int* deg_t    = (int*)ws; ws += NT;
  int* rowptr_t = (int*)ws; ws += NT + 2;
  int* cursor_t = (int*)ws; ws += NT;
  int2* pack_s  = (int2*)ws; ws += (size_t)E * 2;
  int2* pack_t  = (int2*)ws; ws += (size_t)E * 2;

  float* S0_out = (float*)d_out;
  float* SL_out = S0_out + NN;

  // ---- CSR build (reused by 3 aggregations per side) ----
  hipMemsetAsync(deg_s, 0, NT * sizeof(int), stream);
  hipMemsetAsync(deg_t, 0, NT * sizeof(int), stream);
  degree_k<<<E / 256, 256, 0, stream>>>(dst_s, deg_s);
  degree_k<<<E / 256, 256, 0, stream>>>(dst_t, deg_t);
  scan_nodes<<<1, 256, 0, stream>>>(deg_s, rowptr_s, cursor_s);
  scan_nodes<<<1, 256, 0, stream>>>(deg_t, rowptr_t, cursor_t);
  fill_csr<<<E / 256, 256, 0, stream>>>(src_s, dst_s, ea_s, cursor_s, pack_s);
  fill_csr<<<E / 256, 256, 0, stream>>>(src_t, dst_t, ea_t, cursor_t, pack_t);

  // ---- psi_1 ----
  psi1_project<<<NT, 64, 0, stream>>>(x_s, W1r, W1n, b1, xr_s, xn_s);
  psi1_project<<<NT, 64, 0, stream>>>(x_t, W1r, W1n, b1, xr_t, xn_t);
  gather64<<<NT * 16 / 256, 256, 0, stream>>>(xn_s, rowptr_s, pack_s, ag_s);
  gather64<<<NT * 16 / 256, 256, 0, stream>>>(xn_t, rowptr_t, pack_t, ag_t);
  gemm_score64<<<dim3(16, 16, B), 256, 0, stream>>>(xr_s, ag_s, xr_t, ag_t, Shat);

  // ---- consensus steps ----
  for (int step = 0; step < 2; ++step) {
    float* S = (step == 0) ? S0_out : Sbuf;          // step-0 softmax IS S_0
    softmax512<<<B * N, 256, 0, stream>>>(Shat, S);
    const float* rs = r_all + (size_t)step * NT * R_IN;
    rt_kernel<<<dim3(16, B), 256, 0, stream>>>(S, rs, rt_b);
    gather32<<<NT * 8 / 256, 256, 0, stream>>>(rs, rowptr_s, pack_s, ag2s);
    gather32<<<NT * 8 / 256, 256, 0, stream>>>(rt_b, rowptr_t, pack_t, ag2t);
    psi2_dense<<<NT / 8, 256, 0, stream>>>(rs, ag2s, W2r, W2n, b2, Wm1, bm1, 1, Psb);
    psi2_dense<<<NT / 8, 256, 0, stream>>>(rt_b, ag2t, W2r, W2n, b2, Wm1, bm1, 0, Ptb);
    consensus_update<<<dim3(16, 16, B), 256, 0, stream>>>(Psb, Ptb, Wm2, bm2, Shat);
  }
  softmax512<<<B * N, 256, 0, stream>>>(Shat, SL_out);
}